// Round 2
// baseline (7963.235 us; speedup 1.0000x reference)
//
#include <hip/hip_runtime.h>
#include <hip/hip_bf16.h>

#define BB 64
#define TT 2048
#define II 128
#define HH 256
#define GG 768   // 3*H

typedef _Float16 h2 __attribute__((ext_vector_type(2)));
typedef _Float16 half8 __attribute__((ext_vector_type(8)));
typedef float f32x4 __attribute__((ext_vector_type(4)));
union U32H2 { unsigned int u; h2 h; };

static __device__ __forceinline__ float fdot2f(unsigned int w, h2 hv, float acc){
#if __has_builtin(__builtin_amdgcn_fdot2)
    U32H2 c; c.u = w;
    return __builtin_amdgcn_fdot2(c.h, hv, acc, false);
#else
    U32H2 c; c.u = w;
    return acc + (float)c.h.x * (float)hv.x + (float)c.h.y * (float)hv.y;
#endif
}

// ---------------------------------------------------------------------------
// Phase 0a: W_hh [768][256] f32 -> packed f16 pairs, transposed:
// Wt[kk][g] = pack(W_hh[g][2kk], W_hh[g][2kk+1]), kk in [0,128), g in [0,768)
// ---------------------------------------------------------------------------
__global__ void conv_whh(const float* __restrict__ Whh, unsigned int* __restrict__ Wt){
    int idx = blockIdx.x * 256 + threadIdx.x;   // 98304 total
    int kk = idx / GG;
    int g  = idx - kk * GG;
    float a = Whh[g * HH + 2*kk];
    float b = Whh[g * HH + 2*kk + 1];
    U32H2 c; c.h.x = (_Float16)a; c.h.y = (_Float16)b;
    Wt[idx] = c.u;
}

// Phase 0b: W_ih [768][128] f32 -> f16 (same layout)
__global__ void conv_wih(const float* __restrict__ Wih, _Float16* __restrict__ Wh){
    int idx = blockIdx.x * 256 + threadIdx.x;   // 98304 total
    Wh[idx] = (_Float16)Wih[idx];
}

// ---------------------------------------------------------------------------
// Phase 1: gi[bt][g] = sum_k x[bt][k]*W_ih[g][k] + b_ih[g]  via f16 MFMA.
// Block = 256 thr (4 waves). Each wave: M=16 rows, N=192 cols, K=128.
// 192-wide blocks (vs 64) cut the x re-read from 12x to 4x.
// ---------------------------------------------------------------------------
__global__ __launch_bounds__(256) void gi_mfma(const float* __restrict__ x,
                                               const _Float16* __restrict__ Wh,
                                               const float* __restrict__ bih,
                                               _Float16* __restrict__ gi){
    const int wave = threadIdx.x >> 6;
    const int lane = threadIdx.x & 63;
    const int l16  = lane & 15, q = lane >> 4;
    const int m    = blockIdx.x * 64 + wave * 16 + l16;   // bt row for A frag
    const int n0   = blockIdx.y * 192;                     // g col base
    f32x4 acc[12] = {};
    #pragma unroll
    for (int s = 0; s < 4; ++s){                           // K steps of 32
        const float* xp = x + (size_t)m * II + s*32 + q*8;
        float4 a0 = *(const float4*)xp;
        float4 a1 = *(const float4*)(xp + 4);
        half8 af = { (_Float16)a0.x,(_Float16)a0.y,(_Float16)a0.z,(_Float16)a0.w,
                     (_Float16)a1.x,(_Float16)a1.y,(_Float16)a1.z,(_Float16)a1.w };
        #pragma unroll
        for (int t = 0; t < 12; ++t){                      // N tiles of 16
            const _Float16* wp = Wh + (size_t)(n0 + t*16 + l16) * II + s*32 + q*8;
            half8 bf = *(const half8*)wp;
            acc[t] = __builtin_amdgcn_mfma_f32_16x16x32_f16(af, bf, acc[t], 0, 0, 0);
        }
    }
    // D layout: col = lane&15 (n), row = (lane>>4)*4 + reg (m)
    #pragma unroll
    for (int t = 0; t < 12; ++t){
        int n = n0 + t*16 + l16;
        float bv = bih[n];
        #pragma unroll
        for (int r = 0; r < 4; ++r){
            int row = blockIdx.x*64 + wave*16 + q*4 + r;
            gi[(size_t)row * GG + n] = (_Float16)(acc[t][r] + bv);
        }
    }
}

// ---------------------------------------------------------------------------
// Phase 2: recurrence. One block per batch element, 1024 threads (16 waves).
//   j = tid>>2 (hidden out), q = tid&3 (k-quarter: pairs [32q,32q+32)).
//   The 4 K-partials for one j live in a quad -> reduce via __shfl_xor (DPP),
//   no LDS partials, no serial wave, ONE barrier/step (h double-buffered).
//   h kept in LDS as f16, 4 bank-shifted replicas (stride 272 f16) so the
//   quarter-strided uint4 broadcast reads are bank-conflict-free:
//   lane q reads replica q at its own quarter: byte addr q*544 + q*128 + 16mm
//   -> bank 8q + 4mm (mod 32), disjoint across q.
//   gi folded into partials pre-reduce: lane q loads gate q (q<3), prefetched
//   one step ahead.
// ---------------------------------------------------------------------------
#define HREP 272               // f16 stride between replicas (544 B: +8 banks)
#define HBUF (4 * HREP)        // one time-buffer: 4 replicas

__global__ __launch_bounds__(1024, 4) void gru_rec(
        const unsigned int* __restrict__ Wt,   // [128][768] packed f16 pairs
        const _Float16* __restrict__ gi,       // [64][2048][768]
        const float* __restrict__ bhh,         // [768]
        float* __restrict__ hid)               // [64][2048][256]
{
    const int b   = blockIdx.x;
    const int tid = threadIdx.x;
    const int j   = tid >> 2;      // 0..255 hidden index
    const int q   = tid & 3;       // 0..3 k-quarter

    unsigned int Wr[32], Wz[32], Wn[32];
    {
        const unsigned int* Wb = Wt + q * 32 * GG;
        #pragma unroll
        for (int m = 0; m < 32; ++m){
            Wr[m] = Wb[m * GG + j];
            Wz[m] = Wb[m * GG + j + 256];
            Wn[m] = Wb[m * GG + j + 512];
        }
    }
    // bias for the gate this lane "owns" in the pre-reduce fold
    float bq = (q < 3) ? bhh[q * 256 + j] : 0.f;

    __shared__ __align__(16) _Float16 hps[2 * HBUF];
    for (int i = tid; i < 2 * HBUF; i += 1024) hps[i] = (_Float16)0.f;

    const _Float16* gib = gi + (size_t)b * TT * GG;
    float* hob = hid + (size_t)b * TT * HH;

    float h_prev = 0.f;
    _Float16 gcur = (q < 3) ? gib[q * 256 + j] : (_Float16)0.f;   // gi[t=0]

    // lane q reads ITS quarter [64q, 64q+64) from replica q
    const uint4* rd0 = (const uint4*)(hps + q * HREP + q * 64);
    const uint4* rd1 = (const uint4*)(hps + HBUF + q * HREP + q * 64);
    _Float16* wr0 = hps + q * HREP + j;
    _Float16* wr1 = hps + HBUF + q * HREP + j;

    __syncthreads();

    for (int t = 0; t < TT; ++t){
        // prefetch next step's gi (independent of h -> full step of latency)
        int tn = (t + 1 < TT) ? t + 1 : t;
        _Float16 gnext = (q < 3) ? gib[(size_t)tn * GG + q * 256 + j]
                                 : (_Float16)0.f;

        // h broadcast read: 8 x ds_read_b128, replica q of buffer t&1
        const uint4* hv = (t & 1) ? rd1 : rd0;
        uint4 hreg[8];
        #pragma unroll
        for (int mm = 0; mm < 8; ++mm) hreg[mm] = hv[mm];

        // fold gi + bias into this lane's partial before the quad-reduce.
        // n-gate's gi must stay OUTSIDE the r*(.) product -> carry gn.
        float g = (float)gcur;
        float ar = 0.f, az = 0.f, an = 0.f, gn = 0.f;
        if      (q == 0) ar = bq + g;
        else if (q == 1) az = bq + g;
        else if (q == 2) { an = bq; gn = g; }

        #pragma unroll
        for (int mm = 0; mm < 8; ++mm){
            union { uint4 v; h2 p[4]; } hh;
            hh.v = hreg[mm];
            #pragma unroll
            for (int p = 0; p < 4; ++p){
                ar = fdot2f(Wr[4*mm + p], hh.p[p], ar);
                az = fdot2f(Wz[4*mm + p], hh.p[p], az);
                an = fdot2f(Wn[4*mm + p], hh.p[p], an);
            }
        }

        // quad butterfly: all 4 lanes end with the full sums
        ar += __shfl_xor(ar, 1); ar += __shfl_xor(ar, 2);
        az += __shfl_xor(az, 1); az += __shfl_xor(az, 2);
        an += __shfl_xor(an, 1); an += __shfl_xor(an, 2);
        gn += __shfl_xor(gn, 1); gn += __shfl_xor(gn, 2);

        // gate math, redundant across the quad (lanes, not time)
        float r = 1.f / (1.f + __expf(-ar));
        float z = 1.f / (1.f + __expf(-az));
        float tin = gn + r * an;
        tin = fminf(15.f, fmaxf(-15.f, tin));
        float e2 = __expf(2.f * tin);
        float n = (e2 - 1.f) / (e2 + 1.f);
        float hn = (1.f - z) * n + z * h_prev;
        h_prev = hn;

        // write h_t into buffer (t+1)&1, each lane its own replica
        *((t & 1) ? wr0 : wr1) = (_Float16)hn;
        if (q == 3) hob[(size_t)t * HH + j] = hn;   // the gi-idle lane stores

        gcur = gnext;
        __syncthreads();
    }
}

// ---------------------------------------------------------------------------
// Phase 3: outputs[bt] = dot(hiddens[bt], W_o) + b_o.  One wave per bt.
// ---------------------------------------------------------------------------
__global__ __launch_bounds__(256) void out_proj(const float* __restrict__ hid,
                                                const float* __restrict__ Wo,
                                                const float* __restrict__ bo,
                                                float* __restrict__ outp){
    const int w = threadIdx.x >> 6, l = threadIdx.x & 63;
    const size_t bt = (size_t)blockIdx.x * 4 + w;
    const float4 hv = ((const float4*)(hid + bt * HH))[l];
    const float4 wv = ((const float4*)Wo)[l];
    float s = hv.x*wv.x + hv.y*wv.y + hv.z*wv.z + hv.w*wv.w;
    #pragma unroll
    for (int off = 32; off > 0; off >>= 1) s += __shfl_down(s, off, 64);
    if (l == 0) outp[bt] = s + bo[0];
}

// ---------------------------------------------------------------------------
extern "C" void kernel_launch(void* const* d_in, const int* in_sizes, int n_in,
                              void* d_out, int out_size, void* d_ws, size_t ws_size,
                              hipStream_t stream) {
    const float* x   = (const float*)d_in[0];
    const float* Wih = (const float*)d_in[1];
    const float* Whh = (const float*)d_in[2];
    const float* bih = (const float*)d_in[3];
    const float* bhh = (const float*)d_in[4];
    const float* Wo  = (const float*)d_in[5];
    const float* bo  = (const float*)d_in[6];

    float* outputs = (float*)d_out;                      // [64][2048][1]
    float* hiddens = (float*)d_out + (size_t)BB * TT;    // [64][2048][256]

    // Workspace: Wt (393216 B) | Wih f16 (196608 B) | gi f16 (201326592 B)
    unsigned int* Wt = (unsigned int*)d_ws;
    _Float16* Wh = (_Float16*)((char*)d_ws + 128 * GG * sizeof(unsigned int));
    _Float16* gi = (_Float16*)((char*)Wh + (size_t)GG * II * sizeof(_Float16));

    conv_whh<<<dim3(98304 / 256), dim3(256), 0, stream>>>(Whh, Wt);
    conv_wih<<<dim3(98304 / 256), dim3(256), 0, stream>>>(Wih, Wh);
    gi_mfma <<<dim3((BB * TT) / 64, GG / 192), dim3(256), 0, stream>>>(x, Wh, bih, gi);
    gru_rec <<<dim3(BB), dim3(1024), 0, stream>>>(Wt, gi, bhh, hiddens);
    out_proj<<<dim3((BB * TT) / 4), dim3(256), 0, stream>>>(hiddens, Wo, bo, outputs);
}

// Round 3
// 4191.565 us; speedup vs baseline: 1.8998x; 1.8998x over previous
//
#include <hip/hip_runtime.h>
#include <hip/hip_bf16.h>

#define BB 64
#define TT 2048
#define II 128
#define HH 256
#define GG 768   // 3*H

typedef _Float16 h2 __attribute__((ext_vector_type(2)));
typedef _Float16 half8 __attribute__((ext_vector_type(8)));
typedef float f32x4 __attribute__((ext_vector_type(4)));
union U32H2 { unsigned int u; h2 h; };

static __device__ __forceinline__ float fdot2f(unsigned int w, h2 hv, float acc){
#if __has_builtin(__builtin_amdgcn_fdot2)
    U32H2 c; c.u = w;
    return __builtin_amdgcn_fdot2(c.h, hv, acc, false);
#else
    U32H2 c; c.u = w;
    return acc + (float)c.h.x * (float)hv.x + (float)c.h.y * (float)hv.y;
#endif
}

// ---------------------------------------------------------------------------
// Phase 0a: W_hh [768][256] f32 -> packed f16 pairs, transposed:
// Wt[kk][g] = pack(W_hh[g][2kk], W_hh[g][2kk+1]), kk in [0,128), g in [0,768)
// ---------------------------------------------------------------------------
__global__ void conv_whh(const float* __restrict__ Whh, unsigned int* __restrict__ Wt){
    int idx = blockIdx.x * 256 + threadIdx.x;   // 98304 total
    int kk = idx / GG;
    int g  = idx - kk * GG;
    float a = Whh[g * HH + 2*kk];
    float b = Whh[g * HH + 2*kk + 1];
    U32H2 c; c.h.x = (_Float16)a; c.h.y = (_Float16)b;
    Wt[idx] = c.u;
}

// Phase 0b: W_ih [768][128] f32 -> f16 (same layout)
__global__ void conv_wih(const float* __restrict__ Wih, _Float16* __restrict__ Wh){
    int idx = blockIdx.x * 256 + threadIdx.x;   // 98304 total
    Wh[idx] = (_Float16)Wih[idx];
}

// ---------------------------------------------------------------------------
// Phase 1: gi[bt][g] = sum_k x[bt][k]*W_ih[g][k] + b_ih[g]  via f16 MFMA.
// Block = 256 thr (4 waves). Each wave: M=16 rows, N=192 cols, K=128.
// 192-wide blocks (vs 64) cut the x re-read from 12x to 4x.
// ---------------------------------------------------------------------------
__global__ __launch_bounds__(256) void gi_mfma(const float* __restrict__ x,
                                               const _Float16* __restrict__ Wh,
                                               const float* __restrict__ bih,
                                               _Float16* __restrict__ gi){
    const int wave = threadIdx.x >> 6;
    const int lane = threadIdx.x & 63;
    const int l16  = lane & 15, q = lane >> 4;
    const int m    = blockIdx.x * 64 + wave * 16 + l16;   // bt row for A frag
    const int n0   = blockIdx.y * 192;                     // g col base
    f32x4 acc[12] = {};
    #pragma unroll
    for (int s = 0; s < 4; ++s){                           // K steps of 32
        const float* xp = x + (size_t)m * II + s*32 + q*8;
        float4 a0 = *(const float4*)xp;
        float4 a1 = *(const float4*)(xp + 4);
        half8 af = { (_Float16)a0.x,(_Float16)a0.y,(_Float16)a0.z,(_Float16)a0.w,
                     (_Float16)a1.x,(_Float16)a1.y,(_Float16)a1.z,(_Float16)a1.w };
        #pragma unroll
        for (int t = 0; t < 12; ++t){                      // N tiles of 16
            const _Float16* wp = Wh + (size_t)(n0 + t*16 + l16) * II + s*32 + q*8;
            half8 bf = *(const half8*)wp;
            acc[t] = __builtin_amdgcn_mfma_f32_16x16x32_f16(af, bf, acc[t], 0, 0, 0);
        }
    }
    // D layout: col = lane&15 (n), row = (lane>>4)*4 + reg (m)
    #pragma unroll
    for (int t = 0; t < 12; ++t){
        int n = n0 + t*16 + l16;
        float bv = bih[n];
        #pragma unroll
        for (int r = 0; r < 4; ++r){
            int row = blockIdx.x*64 + wave*16 + q*4 + r;
            gi[(size_t)row * GG + n] = (_Float16)(acc[t][r] + bv);
        }
    }
}

// ---------------------------------------------------------------------------
// Phase 2: recurrence. One block per batch element, 1024 threads (16 waves).
//   j = tid>>2 (hidden out), q = tid&3 (k-quarter: pairs [32q,32q+32)).
//   The 4 K-partials for one j live in a quad -> reduce via __shfl_xor (DPP),
//   no LDS partials, no serial wave, ONE barrier/step (h double-buffered).
//   h kept in LDS as f16, 4 bank-shifted replicas (stride 272 f16); lane q
//   reads replica q at its own quarter -> conflict-free (verified: 0 in PMC).
//   REGISTER BUDGET (128 unified regs/wave at 16 waves/CU): 96 W regs + ~20
//   working. LDS h is read ONE uint4 at a time directly in the dot loop —
//   do NOT stage all 8 into registers first (round-2 did: +32 regs -> scratch
//   spill -> 3.4x slowdown).
// ---------------------------------------------------------------------------
#define HREP 272               // f16 stride between replicas (544 B: +8 banks)
#define HBUF (4 * HREP)        // one time-buffer: 4 replicas

__global__ __launch_bounds__(1024, 4) void gru_rec(
        const unsigned int* __restrict__ Wt,   // [128][768] packed f16 pairs
        const _Float16* __restrict__ gi,       // [64][2048][768]
        const float* __restrict__ bhh,         // [768]
        float* __restrict__ hid)               // [64][2048][256]
{
    const int b   = blockIdx.x;
    const int tid = threadIdx.x;
    const int j   = tid >> 2;      // 0..255 hidden index
    const int q   = tid & 3;       // 0..3 k-quarter

    unsigned int Wr[32], Wz[32], Wn[32];
    {
        const unsigned int* Wb = Wt + q * 32 * GG;
        #pragma unroll
        for (int m = 0; m < 32; ++m){
            Wr[m] = Wb[m * GG + j];
            Wz[m] = Wb[m * GG + j + 256];
            Wn[m] = Wb[m * GG + j + 512];
        }
    }
    // bias for the gate this lane "owns" in the pre-reduce fold
    float bq = (q < 3) ? bhh[q * 256 + j] : 0.f;

    __shared__ __align__(16) _Float16 hps[2 * HBUF];
    for (int i = tid; i < 2 * HBUF; i += 1024) hps[i] = (_Float16)0.f;

    const _Float16* gib = gi + (size_t)b * TT * GG;
    float* hob = hid + (size_t)b * TT * HH;

    float h_prev = 0.f;
    _Float16 gcur = (q < 3) ? gib[q * 256 + j] : (_Float16)0.f;   // gi[t=0]

    // lane q reads ITS quarter [64q, 64q+64) from replica q
    const uint4* rd0 = (const uint4*)(hps + q * HREP + q * 64);
    const uint4* rd1 = (const uint4*)(hps + HBUF + q * HREP + q * 64);
    _Float16* wr0 = hps + q * HREP + j;
    _Float16* wr1 = hps + HBUF + q * HREP + j;

    __syncthreads();

    for (int t = 0; t < TT; ++t){
        // prefetch next step's gi (independent of h -> full step of latency)
        int tn = (t + 1 < TT) ? t + 1 : t;
        _Float16 gnext = (q < 3) ? gib[(size_t)tn * GG + q * 256 + j]
                                 : (_Float16)0.f;

        const uint4* hv = (t & 1) ? rd1 : rd0;

        // fold gi + bias into this lane's partial before the quad-reduce.
        // n-gate's gi must stay OUTSIDE the r*(.) product -> carry gn.
        float g = (float)gcur;
        float ar = 0.f, az = 0.f, an = 0.f, gn = 0.f;
        if      (q == 0) ar = bq + g;
        else if (q == 1) az = bq + g;
        else if (q == 2) { an = bq; gn = g; }

        // LDS read one uint4 at a time, consumed immediately (reg-pressure!)
        #pragma unroll
        for (int mm = 0; mm < 8; ++mm){
            union { uint4 v; h2 p[4]; } hh;
            hh.v = hv[mm];
            #pragma unroll
            for (int p = 0; p < 4; ++p){
                ar = fdot2f(Wr[4*mm + p], hh.p[p], ar);
                az = fdot2f(Wz[4*mm + p], hh.p[p], az);
                an = fdot2f(Wn[4*mm + p], hh.p[p], an);
            }
        }

        // quad butterfly: all 4 lanes end with the full sums
        ar += __shfl_xor(ar, 1); ar += __shfl_xor(ar, 2);
        az += __shfl_xor(az, 1); az += __shfl_xor(az, 2);
        an += __shfl_xor(an, 1); an += __shfl_xor(an, 2);
        gn += __shfl_xor(gn, 1); gn += __shfl_xor(gn, 2);

        // gate math, redundant across the quad (lanes, not time)
        float r = 1.f / (1.f + __expf(-ar));
        float z = 1.f / (1.f + __expf(-az));
        float tin = gn + r * an;
        tin = fminf(15.f, fmaxf(-15.f, tin));
        float e2 = __expf(2.f * tin);
        float n = (e2 - 1.f) / (e2 + 1.f);
        float hn = (1.f - z) * n + z * h_prev;
        h_prev = hn;

        // write h_t into buffer (t+1)&1, each lane its own replica
        *((t & 1) ? wr0 : wr1) = (_Float16)hn;
        if (q == 3) hob[(size_t)t * HH + j] = hn;   // the gi-idle lane stores

        gcur = gnext;
        __syncthreads();
    }
}

// ---------------------------------------------------------------------------
// Phase 3: outputs[bt] = dot(hiddens[bt], W_o) + b_o.  One wave per bt.
// ---------------------------------------------------------------------------
__global__ __launch_bounds__(256) void out_proj(const float* __restrict__ hid,
                                                const float* __restrict__ Wo,
                                                const float* __restrict__ bo,
                                                float* __restrict__ outp){
    const int w = threadIdx.x >> 6, l = threadIdx.x & 63;
    const size_t bt = (size_t)blockIdx.x * 4 + w;
    const float4 hv = ((const float4*)(hid + bt * HH))[l];
    const float4 wv = ((const float4*)Wo)[l];
    float s = hv.x*wv.x + hv.y*wv.y + hv.z*wv.z + hv.w*wv.w;
    #pragma unroll
    for (int off = 32; off > 0; off >>= 1) s += __shfl_down(s, off, 64);
    if (l == 0) outp[bt] = s + bo[0];
}

// ---------------------------------------------------------------------------
extern "C" void kernel_launch(void* const* d_in, const int* in_sizes, int n_in,
                              void* d_out, int out_size, void* d_ws, size_t ws_size,
                              hipStream_t stream) {
    const float* x   = (const float*)d_in[0];
    const float* Wih = (const float*)d_in[1];
    const float* Whh = (const float*)d_in[2];
    const float* bih = (const float*)d_in[3];
    const float* bhh = (const float*)d_in[4];
    const float* Wo  = (const float*)d_in[5];
    const float* bo  = (const float*)d_in[6];

    float* outputs = (float*)d_out;                      // [64][2048][1]
    float* hiddens = (float*)d_out + (size_t)BB * TT;    // [64][2048][256]

    // Workspace: Wt (393216 B) | Wih f16 (196608 B) | gi f16 (201326592 B)
    unsigned int* Wt = (unsigned int*)d_ws;
    _Float16* Wh = (_Float16*)((char*)d_ws + 128 * GG * sizeof(unsigned int));
    _Float16* gi = (_Float16*)((char*)Wh + (size_t)GG * II * sizeof(_Float16));

    conv_whh<<<dim3(98304 / 256), dim3(256), 0, stream>>>(Whh, Wt);
    conv_wih<<<dim3(98304 / 256), dim3(256), 0, stream>>>(Wih, Wh);
    gi_mfma <<<dim3((BB * TT) / 64, GG / 192), dim3(256), 0, stream>>>(x, Wh, bih, gi);
    gru_rec <<<dim3(BB), dim3(1024), 0, stream>>>(Wt, gi, bhh, hiddens);
    out_proj<<<dim3((BB * TT) / 4), dim3(256), 0, stream>>>(hiddens, Wo, bo, outputs);
}